// Round 9
// baseline (623.260 us; speedup 1.0000x reference)
//
#include <hip/hip_runtime.h>
#include <hip/hip_bf16.h>
#include <cstdint>

typedef __attribute__((ext_vector_type(8))) short bf16x8;   // 8 bf16 (4 VGPRs)
typedef __attribute__((ext_vector_type(4))) short bf16x4;   // 4 bf16 (8 B)
typedef __attribute__((ext_vector_type(4))) float f32x4;    // MFMA C/D

#define BN_EPS 1e-5f
#define PROWS 16896   // 128*132 floats per (c) plane of P

// ---------------------------------------------------------------------------
// prow plane (512 threads): P[c][r][x] = exclusive x-prefix of input row r.
// [r][0]=0, [r][x+1]=sum_{x'<=x}, cols 129..131 zeroed. NO y-cumsum (the
// fused kernel telescopes rings via E += P[y+j] + P[y-j] in LDS).
// ---------------------------------------------------------------------------
__device__ __forceinline__ void prow_plane(const float* __restrict__ xp,
                                           float* __restrict__ Pg, int t)
{
  __shared__ float tile[16384];
  __shared__ float csA[512];

  for (int i4 = t; i4 < 4096; i4 += 512) {
    int r = i4 >> 5;
    int g = i4 & 31;
    float4 v = *(const float4*)(xp + (size_t)r * 128 + g * 4);
    *(float4*)(tile + r * 128 + ((g ^ (r & 31)) << 2)) = v;
  }
  __syncthreads();

  int r = t & 127, ch = t >> 7;
  {
    float carry = 0.f;
#pragma unroll
    for (int g8 = 0; g8 < 8; ++g8) {
      int g = ch * 8 + g8;
      float* p = tile + r * 128 + ((g ^ (r & 31)) << 2);
      float4 v = *(float4*)p;
      float s0 = carry + v.x, s1 = s0 + v.y, s2 = s1 + v.z, s3 = s2 + v.w;
      float4 o; o.x = s0; o.y = s1; o.z = s2; o.w = s3;
      *(float4*)p = o;
      carry = s3;
    }
    csA[r * 4 + ch] = carry;
  }
  __syncthreads();
  if (ch > 0) {
    float offs = csA[r * 4 + 0];
    if (ch > 1) offs += csA[r * 4 + 1];
    if (ch > 2) offs += csA[r * 4 + 2];
#pragma unroll
    for (int g8 = 0; g8 < 8; ++g8) {
      int g = ch * 8 + g8;
      float* p = tile + r * 128 + ((g ^ (r & 31)) << 2);
      float4 v = *(float4*)p;
      v.x += offs; v.y += offs; v.z += offs; v.w += offs;
      *(float4*)p = v;
    }
  }
  if (t < 128) {                 // row t: col 0 and pads 129..131
    float* rp = Pg + (size_t)t * 132;
    rp[0] = 0.f; rp[129] = 0.f; rp[130] = 0.f; rp[131] = 0.f;
  }
  __syncthreads();

  int xcol = t & 127, rc = t >> 7;
  int gc = xcol >> 2, wc = xcol & 3;
#pragma unroll
  for (int r8 = 0; r8 < 32; ++r8) {
    int rr = rc * 32 + r8;
    Pg[rr * 132 + xcol + 1] = tile[rr * 128 + ((gc ^ (rr & 31)) << 2) + wc];
  }
}

// ---------------------------------------------------------------------------
// prepsat: blocks [0,512) prep1; [512,608) prep2; [608,608+nplanes) P rows.
// ---------------------------------------------------------------------------
__global__ __launch_bounds__(512) void prepsat_kernel(
    const float* __restrict__ W1, const float* __restrict__ cb1,
    const float* __restrict__ g1, const float* __restrict__ be1,
    const float* __restrict__ mu1, const float* __restrict__ va1,
    const float* __restrict__ W2, const float* __restrict__ cb2,
    const float* __restrict__ g2, const float* __restrict__ be2,
    const float* __restrict__ mu2, const float* __restrict__ va2,
    const float* __restrict__ x,
    __hip_bfloat16* __restrict__ V, float* __restrict__ b1e,
    __hip_bfloat16* __restrict__ W2e, float* __restrict__ b2e,
    float* __restrict__ P, int nplanes)
{
  int blk = blockIdx.x;
  int t = threadIdx.x;
  if (blk < 512) {
    __shared__ float red[8];
    int o = blk;
    const float* wrow = W1 + (size_t)o * 1248;
    float acc = 0.f;
    for (int i = t; i < 1248; i += 512) {
      float s = g1[i] * rsqrtf(va1[i] + BN_EPS);
      float w = wrow[i];
      acc += w * (be1[i] - mu1[i] * s);
      float g = w * s;
      float gn = 0.f;
      if (i < 1152) {
        float sn = g1[i + 96] * rsqrtf(va1[i + 96] + BN_EPS);
        gn = wrow[i + 96] * sn;
      }
      V[(size_t)o * 1248 + i] = __float2bfloat16(g - gn);
    }
    for (int d = 32; d > 0; d >>= 1) acc += __shfl_down(acc, d);
    int lane = t & 63, wvv = t >> 6;
    if (lane == 0) red[wvv] = acc;
    __syncthreads();
    if (t == 0) {
      float s = cb1[o];
#pragma unroll
      for (int i = 0; i < 8; ++i) s += red[i];
      b1e[o] = s;
    }
  } else if (blk < 608) {
    __shared__ float red2[8];
    int o = blk - 512;
    const float* wrow = W2 + (size_t)o * 512;
    float acc;
    {
      int j = t;
      float s = g2[j] * rsqrtf(va2[j] + BN_EPS);
      float wv = wrow[j];
      acc = wv * (be2[j] - mu2[j] * s);
      W2e[(size_t)o * 512 + j] = __float2bfloat16(wv * s);
    }
    for (int d = 32; d > 0; d >>= 1) acc += __shfl_down(acc, d);
    int lane = t & 63, wvv = t >> 6;
    if (lane == 0) red2[wvv] = acc;
    __syncthreads();
    if (t == 0) {
      float s = cb2[o];
#pragma unroll
      for (int i = 0; i < 8; ++i) s += red2[i];
      b2e[o] = s;
    }
  } else {
    int plane = blk - 608;
    if (plane < nplanes)
      prow_plane(x + (size_t)plane * 16384, P + (size_t)plane * PROWS, t);
  }
}

__global__ __launch_bounds__(512) void prowonly_kernel(
    const float* __restrict__ x, float* __restrict__ P)
{
  prow_plane(x + (size_t)blockIdx.x * 16384,
             P + (size_t)blockIdx.x * PROWS, threadIdx.x);
}

// ---------------------------------------------------------------------------
// fused v12: TWO desynced blocks per CU (the stall-filling lever R8 proved
// is missing: all pipes <20%, issue ~7%, barrier/conflict fixes were no-ops).
// Block = (img,y, o1-half mh): o1 256 x px 128. 512 thr / 8 waves /
// __launch_bounds__(512,4) -> 128 regs/wave: acc[4][4]=64 + ~24 staging +
// ~32 frags. Wave = (wm: 4 o1-slabs of 64) x (wn: 2 px-halves of 64).
// E single-buffer in-place: E(0)=P[y]; E(j+1)=E(j)+P[y+j+1]+P[y-j+1]
// (P = x-prefix rows; both halves of a row read the SAME P rows and are
// paired on one XCD -> L2 hits, avoiding R6's px-split FETCH explosion).
// LDS: E 50688 + As 27648 = 78336 -> exactly 2 blocks/CU; their barriers
// are independent -> one block's waves run while the other stalls/drains.
// gemm2: each block holds half of gemm2's K -> f32 atomicAdd partial out
// (out pre-zeroed with a captured hipMemsetAsync; relu/bias exact per block
// since gemm1 splits only M). Ring phases (2 barriers, As single):
//  B: { el(c0) mfma0 rmw(c0) el(c1) mfma1 rmw(c1) el(c2) mfma2 rmw(c2) } bar
//  A: { build(j+1) } bar.
// ---------------------------------------------------------------------------
__global__ __launch_bounds__(512, 4) void fused7_kernel(
    const float* __restrict__ P, const __hip_bfloat16* __restrict__ V,
    const float* __restrict__ b1e, const __hip_bfloat16* __restrict__ W2e,
    const float* __restrict__ b2e, float* __restrict__ out, int nb, int b0)
{
  extern __shared__ __align__(16) char smem[];
  float* E = (float*)smem;                                   // 96*132 f32
  __hip_bfloat16* As = (__hip_bfloat16*)(smem + 50688);      // [128][108]

  int b = blockIdx.x;
  int rows = nb * 128, per_xcd = rows >> 3;
  int xcd = b & 7, rest = b >> 3;
  int mh = rest & 1;                          // o1-half
  int ridx = xcd * per_xcd + (rest >> 1);     // halves of a row adjacent
  int bL = ridx >> 7, y = ridx & 127;

  int t = threadIdx.x;
  int lane = t & 63, wv = t >> 6;             // 8 waves
  int wm = wv & 3, wn = wv >> 2;              // o1-slab(64) x px-half(64)
  int lr = lane & 15, quad = lane >> 4;
  int px = t & 127;                           // build pixel
  int bg = t >> 7;                            // build granule base 0..3

  const float* Pb = P + (size_t)bL * 96 * PROWS;

  f32x4 acc[4][4];
#pragma unroll
  for (int io = 0; io < 4; ++io)
#pragma unroll
    for (int ip = 0; ip < 4; ++ip) acc[io][ip] = (f32x4){0.f, 0.f, 0.f, 0.f};

  // ---- E update machinery: 96ch x 33 granules = 3168 tasks, 7 slots ----
  float4 pa[3], pb[3];

  // load slots [s0,s0+n) of rows y+jr / y-jr (flags block-uniform)
  auto el = [&](int jr, int s0, int n) {
    int ra = y + jr, rb = y - jr;
    bool fa = (ra <= 127), fb = (rb >= 0);
#pragma unroll
    for (int k = 0; k < 3; ++k) {
      if (k >= n) break;
      int idx = (s0 + k) * 512 + t;
      if (idx < 3168) {
        int cl = idx / 33, ck = idx - cl * 33;
        const float* gp = Pb + (size_t)cl * PROWS + ck * 4;
        if (fa) pa[k] = *(const float4*)(gp + ra * 132);
        if (fb) pb[k] = *(const float4*)(gp + rb * 132);
      }
    }
  };

  auto ermw = [&](int jr, int s0, int n) {
    bool fa = (y + jr <= 127), fb = (y - jr >= 0);
#pragma unroll
    for (int k = 0; k < 3; ++k) {
      if (k >= n) break;
      int idx = (s0 + k) * 512 + t;
      if (idx < 3168) {
        int cl = idx / 33, ck = idx - cl * 33;
        float* ep = E + cl * 132 + ck * 4;
        float4 v = *(float4*)ep;
        if (fa) { v.x += pa[k].x; v.y += pa[k].y; v.z += pa[k].z; v.w += pa[k].w; }
        if (fb) { v.x += pb[k].x; v.y += pb[k].y; v.z += pb[k].z; v.w += pb[k].w; }
        *(float4*)ep = v;
      }
    }
  };

  // ring 0 init: E = P[y]
  auto einit = [&](int s0, int n) {
#pragma unroll
    for (int k = 0; k < 3; ++k) {
      if (k >= n) break;
      int idx = (s0 + k) * 512 + t;
      if (idx < 3168) {
        int cl = idx / 33, ck = idx - cl * 33;
        pa[k] = *(const float4*)(Pb + (size_t)cl * PROWS + y * 132 + ck * 4);
      }
    }
#pragma unroll
    for (int k = 0; k < 3; ++k) {
      if (k >= n) break;
      int idx = (s0 + k) * 512 + t;
      if (idx < 3168) {
        int cl = idx / 33, ck = idx - cl * 33;
        *(float4*)(E + cl * 132 + ck * 4) = pa[k];
      }
    }
  };

  // build As[px][96] for ring jr (thread: granules bg, bg+4, bg+8)
  auto build = [&](int jr) {
    int x1 = (px - jr < 0) ? 0 : (px - jr);
    int x2 = ((px + jr > 127) ? 127 : (px + jr)) + 1;
#pragma unroll
    for (int k = 0; k < 3; ++k) {
      int g = bg + 4 * k;
      const float* Eb = E + g * 8 * 132;
      union { bf16x8 v; __hip_bfloat16 h8[8]; } pk;
#pragma unroll
      for (int i = 0; i < 8; ++i)
        pk.h8[i] = __float2bfloat16(Eb[i * 132 + x2] - Eb[i * 132 + x1]);
      *(bf16x8*)(As + px * 108 + g * 8) = pk.v;
    }
  };

  // one K-sub-phase: 4 V-frags (global, this o1-half) x 4 As-frags -> 16 MFMA
  auto mfma_sub = [&](int j, int sub) {
    bf16x8 av[4], bs[4];
#pragma unroll
    for (int io = 0; io < 4; ++io)
      av[io] = *(const bf16x8*)(V + (size_t)(mh * 256 + wm * 64 + io * 16 + lr) * 1248
                                + j * 96 + sub * 32 + quad * 8);
#pragma unroll
    for (int ip = 0; ip < 4; ++ip)
      bs[ip] = *(const bf16x8*)(As + (wn * 64 + ip * 16 + lr) * 108 + sub * 32 + quad * 8);
    __builtin_amdgcn_s_setprio(1);
#pragma unroll
    for (int io = 0; io < 4; ++io)
#pragma unroll
      for (int ip = 0; ip < 4; ++ip)
        acc[io][ip] = __builtin_amdgcn_mfma_f32_16x16x32_bf16(
            av[io], bs[ip], acc[io][ip], 0, 0, 0);
    __builtin_amdgcn_s_setprio(0);
  };

  // ---- prologue: E <- P[y] (ring 0); build(0) ----
  einit(0, 3); einit(3, 3); einit(6, 1);
  __syncthreads();
  build(0);
  __syncthreads();

  // ---- main loop ----
  for (int j = 0; j < 13; ++j) {
    int jr = j + 1;
    bool up = (j < 12);
    if (up) el(jr, 0, 2);
    mfma_sub(j, 0);
    if (up) { ermw(jr, 0, 2); el(jr, 2, 2); }
    mfma_sub(j, 1);
    if (up) { ermw(jr, 2, 2); el(jr, 4, 3); }
    mfma_sub(j, 2);
    if (up) ermw(jr, 4, 3);
    __syncthreads();
    if (up) {
      build(jr);
      __syncthreads();
    }
  }

  // ---- epilogue A: bias+relu -> Yst[128 px][264 o1h] bf16 (b64 writes) ----
  __hip_bfloat16* Yst = (__hip_bfloat16*)smem;   // 128*264*2 = 67584 B
#pragma unroll
  for (int io = 0; io < 4; ++io) {
    int o1b = wm * 64 + io * 16 + quad * 4;      // local (half) o1
    float4 bias = *(const float4*)(b1e + mh * 256 + o1b);
#pragma unroll
    for (int ip = 0; ip < 4; ++ip) {
      int pxx = wn * 64 + ip * 16 + lr;
      f32x4 a = acc[io][ip];
      float z0 = a[0] + bias.x; z0 = z0 > 0.f ? z0 : 0.f;
      float z1 = a[1] + bias.y; z1 = z1 > 0.f ? z1 : 0.f;
      float z2 = a[2] + bias.z; z2 = z2 > 0.f ? z2 : 0.f;
      float z3 = a[3] + bias.w; z3 = z3 > 0.f ? z3 : 0.f;
      union { bf16x4 v; __hip_bfloat16 hh[4]; } pk;
      pk.hh[0] = __float2bfloat16(z0); pk.hh[1] = __float2bfloat16(z1);
      pk.hh[2] = __float2bfloat16(z2); pk.hh[3] = __float2bfloat16(z3);
      *(bf16x4*)(Yst + pxx * 264 + o1b) = pk.v;
    }
  }
  __syncthreads();

  // ---- epilogue B: partial out[96 o2][128 px] = W2e[:, K-half] x Yst^T,
  //      atomicAdd f32 (out pre-zeroed; bias added by mh==0 block). ----
  int og = wv >> 2;          // 0,1: o2-half of 48
  int pg = wv & 3;           // px quarter (2 x 16-tiles)
  f32x4 acc2[3][2];
#pragma unroll
  for (int im = 0; im < 3; ++im)
#pragma unroll
    for (int tl = 0; tl < 2; ++tl) acc2[im][tl] = (f32x4){0.f, 0.f, 0.f, 0.f};

  for (int k2 = 0; k2 < 256; k2 += 32) {
    bf16x8 bfr2[2];
#pragma unroll
    for (int tl = 0; tl < 2; ++tl)
      bfr2[tl] = *(const bf16x8*)(Yst + (pg * 32 + tl * 16 + lr) * 264 + k2 + quad * 8);
#pragma unroll
    for (int im = 0; im < 3; ++im) {
      bf16x8 afr2 = *(const bf16x8*)(W2e + (size_t)(og * 48 + im * 16 + lr) * 512
                                     + mh * 256 + k2 + quad * 8);
#pragma unroll
      for (int tl = 0; tl < 2; ++tl)
        acc2[im][tl] = __builtin_amdgcn_mfma_f32_16x16x32_bf16(afr2, bfr2[tl], acc2[im][tl], 0, 0, 0);
    }
  }

  size_t obase = ((size_t)(b0 + bL) * 96) * 16384 + (size_t)y * 128;
#pragma unroll
  for (int im = 0; im < 3; ++im) {
#pragma unroll
    for (int tl = 0; tl < 2; ++tl) {
      int pxx = pg * 32 + tl * 16 + lr;
#pragma unroll
      for (int rr = 0; rr < 4; ++rr) {
        int o2 = og * 48 + im * 16 + quad * 4 + rr;
        float v = acc2[im][tl][rr] + (mh == 0 ? b2e[o2] : 0.f);
        atomicAdd(&out[obase + (size_t)o2 * 16384 + pxx], v);
      }
    }
  }
}

// ---------------------------------------------------------------------------
extern "C" void kernel_launch(void* const* d_in, const int* in_sizes, int n_in,
                              void* d_out, int out_size, void* d_ws, size_t ws_size,
                              hipStream_t stream)
{
  const float* x   = (const float*)d_in[0];
  const float* g1  = (const float*)d_in[1];
  const float* be1 = (const float*)d_in[2];
  const float* mu1 = (const float*)d_in[3];
  const float* va1 = (const float*)d_in[4];
  const float* W1  = (const float*)d_in[5];
  const float* cb1 = (const float*)d_in[6];
  const float* g2  = (const float*)d_in[7];
  const float* be2 = (const float*)d_in[8];
  const float* mu2 = (const float*)d_in[9];
  const float* va2 = (const float*)d_in[10];
  const float* W2  = (const float*)d_in[11];
  const float* cb2 = (const float*)d_in[12];
  float* out = (float*)d_out;

  hipFuncSetAttribute((const void*)fused7_kernel,
                      hipFuncAttributeMaxDynamicSharedMemorySize, 78336);

  char* w = (char*)d_ws;
  __hip_bfloat16* V   = (__hip_bfloat16*)w; w += (size_t)512 * 1248 * 2;
  __hip_bfloat16* W2e = (__hip_bfloat16*)w; w += (size_t)96 * 512 * 2;
  float* b1e = (float*)w; w += 2048;
  float* b2e = (float*)w; w += 512;
  size_t fixed = (size_t)(w - (char*)d_ws);

  const size_t pB = (size_t)96 * PROWS * 4;       // per-batch P bytes
  int nb = (ws_size >= fixed + 4 * pB + 4096) ? 4 : 1;

  float* P = (float*)w;

  // out is accumulated via atomics -> zero it (captured in the graph).
  hipMemsetAsync(out, 0, (size_t)out_size * sizeof(float), stream);

  if (nb == 4) {
    prepsat_kernel<<<992, 512, 0, stream>>>(W1, cb1, g1, be1, mu1, va1,
                                            W2, cb2, g2, be2, mu2, va2,
                                            x, V, b1e, W2e, b2e, P, 384);
    fused7_kernel<<<1024, 512, 78336, stream>>>(P, V, b1e, W2e, b2e, out, 4, 0);
  } else {
    prepsat_kernel<<<608, 512, 0, stream>>>(W1, cb1, g1, be1, mu1, va1,
                                            W2, cb2, g2, be2, mu2, va2,
                                            x, V, b1e, W2e, b2e, P, 0);
    for (int b0 = 0; b0 < 4; ++b0) {
      prowonly_kernel<<<96, 512, 0, stream>>>(x + (size_t)b0 * 96 * 16384, P);
      fused7_kernel<<<256, 512, 78336, stream>>>(P, V, b1e, W2e, b2e, out, 1, b0);
    }
  }
}

// Round 10
// 298.484 us; speedup vs baseline: 2.0881x; 2.0881x over previous
//
#include <hip/hip_runtime.h>
#include <hip/hip_bf16.h>
#include <cstdint>

typedef __attribute__((ext_vector_type(8))) short bf16x8;    // 8 bf16 (4 VGPRs)
typedef __attribute__((ext_vector_type(4))) short bf16x4;    // 4 bf16 (8 B)
typedef __attribute__((ext_vector_type(4))) float f32x4;     // 16x16 MFMA C/D
typedef __attribute__((ext_vector_type(16))) float f32x16;   // 32x32 MFMA C/D

#define BN_EPS 1e-5f

// ---------------------------------------------------------------------------
// sat plane (512 threads): exclusive SAT [129][132] per (b,c) plane.
// Cols 129..131 zeroed (eload granule at x=128 reads them).
// ---------------------------------------------------------------------------
__device__ __forceinline__ void sat_plane(const float* __restrict__ xp,
                                          float* __restrict__ Sg, int t)
{
  __shared__ float tile[16384];
  __shared__ float csA[512];
  __shared__ float csB[512];

  for (int i4 = t; i4 < 4096; i4 += 512) {
    int r = i4 >> 5;
    int g = i4 & 31;
    float4 v = *(const float4*)(xp + (size_t)r * 128 + g * 4);
    *(float4*)(tile + r * 128 + ((g ^ (r & 31)) << 2)) = v;
  }
  __syncthreads();

  int r = t & 127, ch = t >> 7;
  {
    float carry = 0.f;
#pragma unroll
    for (int g8 = 0; g8 < 8; ++g8) {
      int g = ch * 8 + g8;
      float* p = tile + r * 128 + ((g ^ (r & 31)) << 2);
      float4 v = *(float4*)p;
      float s0 = carry + v.x, s1 = s0 + v.y, s2 = s1 + v.z, s3 = s2 + v.w;
      float4 o; o.x = s0; o.y = s1; o.z = s2; o.w = s3;
      *(float4*)p = o;
      carry = s3;
    }
    csA[r * 4 + ch] = carry;
  }
  __syncthreads();
  if (ch > 0) {
    float offs = csA[r * 4 + 0];
    if (ch > 1) offs += csA[r * 4 + 1];
    if (ch > 2) offs += csA[r * 4 + 2];
#pragma unroll
    for (int g8 = 0; g8 < 8; ++g8) {
      int g = ch * 8 + g8;
      float* p = tile + r * 128 + ((g ^ (r & 31)) << 2);
      float4 v = *(float4*)p;
      v.x += offs; v.y += offs; v.z += offs; v.w += offs;
      *(float4*)p = v;
    }
  }
  __syncthreads();

  int xcol = t & 127, rc = t >> 7;
  int gc = xcol >> 2, wc = xcol & 3;
  float regs[32];
  {
    float run = 0.f;
#pragma unroll
    for (int r8 = 0; r8 < 32; ++r8) {
      int rr = rc * 32 + r8;
      run += tile[rr * 128 + ((gc ^ (rr & 31)) << 2) + wc];
      regs[r8] = run;
    }
    csB[xcol * 4 + rc] = run;
  }
  if (t < 132) Sg[t] = 0.f;                 // row 0, cols 0..131
  if (t < 128) Sg[(t + 1) * 132] = 0.f;     // col 0
  if (t < 128) {                            // pad cols 129..131
    float* rp = Sg + (size_t)(t + 1) * 132;
    rp[129] = 0.f; rp[130] = 0.f; rp[131] = 0.f;
  }
  __syncthreads();

  float offs = 0.f;
  if (rc > 0) offs += csB[xcol * 4 + 0];
  if (rc > 1) offs += csB[xcol * 4 + 1];
  if (rc > 2) offs += csB[xcol * 4 + 2];
#pragma unroll
  for (int r8 = 0; r8 < 32; ++r8) {
    int rr = rc * 32 + r8;
    Sg[(rr + 1) * 132 + xcol + 1] = regs[r8] + offs;
  }
}

// ---------------------------------------------------------------------------
// prepsat: blocks [0,512) prep1; [512,608) prep2; [608,608+nplanes) sat.
// ---------------------------------------------------------------------------
__global__ __launch_bounds__(512) void prepsat_kernel(
    const float* __restrict__ W1, const float* __restrict__ cb1,
    const float* __restrict__ g1, const float* __restrict__ be1,
    const float* __restrict__ mu1, const float* __restrict__ va1,
    const float* __restrict__ W2, const float* __restrict__ cb2,
    const float* __restrict__ g2, const float* __restrict__ be2,
    const float* __restrict__ mu2, const float* __restrict__ va2,
    const float* __restrict__ x,
    __hip_bfloat16* __restrict__ V, float* __restrict__ b1e,
    __hip_bfloat16* __restrict__ W2e, float* __restrict__ b2e,
    float* __restrict__ SAT, int nplanes)
{
  int blk = blockIdx.x;
  int t = threadIdx.x;
  if (blk < 512) {
    __shared__ float red[8];
    int o = blk;
    const float* wrow = W1 + (size_t)o * 1248;
    float acc = 0.f;
    for (int i = t; i < 1248; i += 512) {
      float s = g1[i] * rsqrtf(va1[i] + BN_EPS);
      float w = wrow[i];
      acc += w * (be1[i] - mu1[i] * s);
      float g = w * s;
      float gn = 0.f;
      if (i < 1152) {
        float sn = g1[i + 96] * rsqrtf(va1[i + 96] + BN_EPS);
        gn = wrow[i + 96] * sn;
      }
      V[(size_t)o * 1248 + i] = __float2bfloat16(g - gn);
    }
    for (int d = 32; d > 0; d >>= 1) acc += __shfl_down(acc, d);
    int lane = t & 63, wvv = t >> 6;
    if (lane == 0) red[wvv] = acc;
    __syncthreads();
    if (t == 0) {
      float s = cb1[o];
#pragma unroll
      for (int i = 0; i < 8; ++i) s += red[i];
      b1e[o] = s;
    }
  } else if (blk < 608) {
    __shared__ float red2[8];
    int o = blk - 512;
    const float* wrow = W2 + (size_t)o * 512;
    float acc;
    {
      int j = t;
      float s = g2[j] * rsqrtf(va2[j] + BN_EPS);
      float wv = wrow[j];
      acc = wv * (be2[j] - mu2[j] * s);
      W2e[(size_t)o * 512 + j] = __float2bfloat16(wv * s);
    }
    for (int d = 32; d > 0; d >>= 1) acc += __shfl_down(acc, d);
    int lane = t & 63, wvv = t >> 6;
    if (lane == 0) red2[wvv] = acc;
    __syncthreads();
    if (t == 0) {
      float s = cb2[o];
#pragma unroll
      for (int i = 0; i < 8; ++i) s += red2[i];
      b2e[o] = s;
    }
  } else {
    int plane = blk - 608;
    if (plane < nplanes)
      sat_plane(x + (size_t)plane * 16384, SAT + (size_t)plane * 17028, t);
  }
}

__global__ __launch_bounds__(512) void satonly_kernel(
    const float* __restrict__ x, float* __restrict__ SAT)
{
  sat_plane(x + (size_t)blockIdx.x * 16384,
            SAT + (size_t)blockIdx.x * 17028, threadIdx.x);
}

// ---------------------------------------------------------------------------
// fused v13 = R8's fused6 (verified 194.9 us) with gemm1 moved to
// mfma_f32_32x32x16_bf16 + a one-k-step-ahead V register pipeline:
//  - per-k-step live frags drop 48 -> 24 regs, funding av0/av1 ping-pong
//    (32 regs) within the same 256-reg budget (acc stays 128).
//  - 6 k-steps of K=16 per ring; av for step s+1 issued BEFORE step s's
//    MFMAs (register loads legally pipeline; last step prefetches next
//    ring's k0 across the barrier).
//  - 32x32 µbench 2382 vs 2075 TF: ~13% less matrix-pipe time.
// eload/ewrite/build/As(stride108)/1-barrier-ring/epilogues: R8-identical.
// A-frag: lane=(row=l&31, khalf=l>>5), 8 bf16. B-frag: lane=(col=l&31,
// khalf), 8 bf16. C/D: col=l&31, row=(reg&3)+8*(reg>>2)+4*(l>>5) [m74/m101].
// ---------------------------------------------------------------------------
__global__ __launch_bounds__(512, 2) void fused8_kernel(
    const float* __restrict__ SAT, const __hip_bfloat16* __restrict__ V,
    const float* __restrict__ b1e, const __hip_bfloat16* __restrict__ W2e,
    const float* __restrict__ b2e, float* __restrict__ out, int nb, int b0)
{
  extern __shared__ __align__(16) char smem[];
  float* E0 = (float*)smem;                                  // 96*132 fp32
  float* E1 = (float*)(smem + 50688);
  __hip_bfloat16* As0 = (__hip_bfloat16*)(smem + 101376);    // [128][108]
  __hip_bfloat16* As1 = (__hip_bfloat16*)(smem + 129024);

  int blk = blockIdx.x;
  int rows_per_xcd = (nb * 128) >> 3;
  int r = (blk & 7) * rows_per_xcd + (blk >> 3);
  int bL = r >> 7, y = r & 127;

  int t = threadIdx.x;
  int lane = t & 63, wv = t >> 6;              // 8 waves
  int wo = wv >> 1, wp = wv & 1;               // o1-slab (128), px-half (64)
  int lr = lane & 15, quad = lane >> 4;        // for 16x16 epilogue B
  int cl = lane & 31, kh = lane >> 5;          // for 32x32 gemm1
  int px = t & 127;                            // build pixel
  int bg = t >> 7;                             // build granule base 0..3

  const float* Sb = SAT + (size_t)bL * 96 * 17028;
  const __hip_bfloat16* Vbase = V + (size_t)(wo * 128 + cl) * 1248 + kh * 8;

  f32x16 acc[4][2];
#pragma unroll
  for (int mt = 0; mt < 4; ++mt)
#pragma unroll
    for (int nt = 0; nt < 2; ++nt)
#pragma unroll
      for (int e = 0; e < 16; ++e) acc[mt][nt][e] = 0.f;

  // ---- efill staging registers (T14 split: load early, write late) ----
  float4 ea[3], eb[3];
  float ta = 0.f, tb = 0.f;

  auto eload = [&](int jr, int h) {
    int y1 = ((y - jr < 0) ? 0 : (y - jr)) * 132;
    int y2 = (((y + jr > 127) ? 127 : (y + jr)) + 1) * 132;
#pragma unroll
    for (int k = 0; k < 3; ++k) {
      int idx = t + 512 * (h * 3 + k);
      int cc = idx >> 5, ck = idx & 31;
      const float* bp = Sb + (size_t)cc * 17028 + ck * 4;
      ea[k] = *(const float4*)(bp + y2);
      eb[k] = *(const float4*)(bp + y1);
    }
    if (h == 1 && t < 96) {   // x = 128 column tail
      const float* bp = Sb + (size_t)t * 17028 + 128;
      ta = bp[y2];
      tb = bp[y1];
    }
  };

  auto ewrite = [&](float* E, int h) {
#pragma unroll
    for (int k = 0; k < 3; ++k) {
      int idx = t + 512 * (h * 3 + k);
      int cc = idx >> 5, ck = idx & 31;
      float4 d;
      d.x = ea[k].x - eb[k].x; d.y = ea[k].y - eb[k].y;
      d.z = ea[k].z - eb[k].z; d.w = ea[k].w - eb[k].w;
      *(float4*)(E + cc * 132 + ck * 4) = d;
    }
    if (h == 1 && t < 96) E[t * 132 + 128] = ta - tb;
  };

  // build As granules [k0,k1) for ring jr from E (thread: granules bg+4k)
  auto build_k = [&](const float* E, __hip_bfloat16* As, int jr, int k0, int k1) {
    int x1 = (px - jr < 0) ? 0 : (px - jr);
    int x2 = ((px + jr > 127) ? 127 : (px + jr)) + 1;
#pragma unroll
    for (int k = k0; k < k1; ++k) {
      int g = bg + 4 * k;
      const float* Eb = E + g * 8 * 132;
      union { bf16x8 v; __hip_bfloat16 h8[8]; } pk;
#pragma unroll
      for (int i = 0; i < 8; ++i)
        pk.h8[i] = __float2bfloat16(Eb[i * 132 + x2] - Eb[i * 132 + x1]);
      *(bf16x8*)(As + px * 108 + g * 8) = pk.v;
    }
  };

  // V fragment prefetch for (j, ks): 4 M-tiles, b128 each
  auto ldV = [&](bf16x8 (&dst)[4], int j, int ks) {
    const __hip_bfloat16* p = Vbase + j * 96 + ks * 16;
#pragma unroll
    for (int mt = 0; mt < 4; ++mt)
      dst[mt] = *(const bf16x8*)(p + (size_t)mt * 32 * 1248);
  };

  // one K=16 step: optional prefetch of NEXT frag set, then 8 MFMA (4x2)
  auto step = [&](bf16x8 (&cur)[4], bf16x8 (&nxt)[4], int pj, int pk, bool pf,
                  const __hip_bfloat16* As, int ks) {
    if (pf) ldV(nxt, pj, pk);
    bf16x8 bs[2];
#pragma unroll
    for (int nt = 0; nt < 2; ++nt)
      bs[nt] = *(const bf16x8*)(As + (wp * 64 + nt * 32 + cl) * 108 + ks * 16 + kh * 8);
    __builtin_amdgcn_s_setprio(1);
#pragma unroll
    for (int mt = 0; mt < 4; ++mt)
#pragma unroll
      for (int nt = 0; nt < 2; ++nt)
        acc[mt][nt] = __builtin_amdgcn_mfma_f32_32x32x16_bf16(
            cur[mt], bs[nt], acc[mt][nt], 0, 0, 0);
    __builtin_amdgcn_s_setprio(0);
  };

  bf16x8 av0[4], av1[4];

  // ---- prologue: E0 <- ring0; then E1 <- ring1 while As0 <- ring0 ----
  eload(0, 0); ewrite(E0, 0); eload(0, 1); ewrite(E0, 1);
  __syncthreads();
  eload(1, 0); ewrite(E1, 0);
  build_k(E0, As0, 0, 0, 2);
  eload(1, 1); ewrite(E1, 1);
  build_k(E0, As0, 0, 2, 3);
  ldV(av0, 0, 0);                 // k-step pipeline prime
  __syncthreads();

  // ---- main loop: ONE barrier per ring, 6 K=16 steps, av ping-pong ----
  for (int j = 0; j < 13; ++j) {
    float* Ew = (j & 1) ? E1 : E0;                     // ring j+2 target
    const float* Er = (j & 1) ? E0 : E1;               // ring j+1 source
    const __hip_bfloat16* Asr = (j & 1) ? As1 : As0;   // ring j
    __hip_bfloat16* Asw = (j & 1) ? As0 : As1;         // ring j+1
    bool pf = (j < 11), bd = (j < 12);

    if (pf) eload(j + 2, 0);
    step(av0, av1, j, 1, true, Asr, 0);
    step(av1, av0, j, 2, true, Asr, 1);
    if (pf) ewrite(Ew, 0);
    if (bd) build_k(Er, Asw, j + 1, 0, 2);    // staging regs dead here
    if (pf) eload(j + 2, 1);
    step(av0, av1, j, 3, true, Asr, 2);
    step(av1, av0, j, 4, true, Asr, 3);
    if (pf) ewrite(Ew, 1);
    if (bd) build_k(Er, Asw, j + 1, 2, 3);    // staging regs dead here
    step(av0, av1, j, 5, true, Asr, 4);
    step(av1, av0, j + 1, 0, j < 12, Asr, 5); // cross-barrier prefetch
    __syncthreads();
  }

  // ---- epilogue A: bias+relu -> Yst[128 px][520 o1] bf16, b64 writes
  //      (32x32 C layout: col=l&31, row=(reg&3)+8*(reg>>2)+4*(l>>5)) ----
  __hip_bfloat16* Yst = (__hip_bfloat16*)smem;   // 128*520*2 = 133120 B
#pragma unroll
  for (int mt = 0; mt < 4; ++mt) {
#pragma unroll
    for (int q = 0; q < 4; ++q) {
      int o1b = wo * 128 + mt * 32 + q * 8 + kh * 4;
      float4 bias = *(const float4*)(b1e + o1b);
#pragma unroll
      for (int nt = 0; nt < 2; ++nt) {
        int pxx = wp * 64 + nt * 32 + cl;
        f32x16 a = acc[mt][nt];
        float z0 = a[q * 4 + 0] + bias.x; z0 = z0 > 0.f ? z0 : 0.f;
        float z1 = a[q * 4 + 1] + bias.y; z1 = z1 > 0.f ? z1 : 0.f;
        float z2 = a[q * 4 + 2] + bias.z; z2 = z2 > 0.f ? z2 : 0.f;
        float z3 = a[q * 4 + 3] + bias.w; z3 = z3 > 0.f ? z3 : 0.f;
        union { bf16x4 v; __hip_bfloat16 hh[4]; } pk;
        pk.hh[0] = __float2bfloat16(z0); pk.hh[1] = __float2bfloat16(z1);
        pk.hh[2] = __float2bfloat16(z2); pk.hh[3] = __float2bfloat16(z3);
        *(bf16x4*)(Yst + pxx * 520 + o1b) = pk.v;
      }
    }
  }
  __syncthreads();

  // ---- epilogue B: out[96 o2][128 px] = W2e[96][512] x Yst^T (16x16) ----
  int og = wv >> 2;          // 0,1
  int pg = wv & 3;           // 0..3
  f32x4 acc2[3][2];
#pragma unroll
  for (int im = 0; im < 3; ++im)
#pragma unroll
    for (int tl = 0; tl < 2; ++tl) acc2[im][tl] = (f32x4){0.f, 0.f, 0.f, 0.f};

  for (int k2 = 0; k2 < 512; k2 += 32) {
    bf16x8 bfr2[2];
#pragma unroll
    for (int tl = 0; tl < 2; ++tl)
      bfr2[tl] = *(const bf16x8*)(Yst + (pg * 32 + tl * 16 + lr) * 520 + k2 + quad * 8);
#pragma unroll
    for (int im = 0; im < 3; ++im) {
      bf16x8 afr2 = *(const bf16x8*)(W2e + (size_t)(og * 48 + im * 16 + lr) * 512
                                     + k2 + quad * 8);
#pragma unroll
      for (int tl = 0; tl < 2; ++tl)
        acc2[im][tl] = __builtin_amdgcn_mfma_f32_16x16x32_bf16(afr2, bfr2[tl], acc2[im][tl], 0, 0, 0);
    }
  }

  size_t obase = ((size_t)(b0 + bL) * 96) * 16384 + (size_t)y * 128;
#pragma unroll
  for (int im = 0; im < 3; ++im) {
#pragma unroll
    for (int tl = 0; tl < 2; ++tl) {
      int pxx = pg * 32 + tl * 16 + lr;
#pragma unroll
      for (int rr = 0; rr < 4; ++rr) {
        int o2 = og * 48 + im * 16 + quad * 4 + rr;
        out[obase + (size_t)o2 * 16384 + pxx] = acc2[im][tl][rr] + b2e[o2];
      }
    }
  }
}

// ---------------------------------------------------------------------------
extern "C" void kernel_launch(void* const* d_in, const int* in_sizes, int n_in,
                              void* d_out, int out_size, void* d_ws, size_t ws_size,
                              hipStream_t stream)
{
  const float* x   = (const float*)d_in[0];
  const float* g1  = (const float*)d_in[1];
  const float* be1 = (const float*)d_in[2];
  const float* mu1 = (const float*)d_in[3];
  const float* va1 = (const float*)d_in[4];
  const float* W1  = (const float*)d_in[5];
  const float* cb1 = (const float*)d_in[6];
  const float* g2  = (const float*)d_in[7];
  const float* be2 = (const float*)d_in[8];
  const float* mu2 = (const float*)d_in[9];
  const float* va2 = (const float*)d_in[10];
  const float* W2  = (const float*)d_in[11];
  const float* cb2 = (const float*)d_in[12];
  float* out = (float*)d_out;

  hipFuncSetAttribute((const void*)fused8_kernel,
                      hipFuncAttributeMaxDynamicSharedMemorySize, 156672);

  char* w = (char*)d_ws;
  __hip_bfloat16* V   = (__hip_bfloat16*)w; w += (size_t)512 * 1248 * 2;
  __hip_bfloat16* W2e = (__hip_bfloat16*)w; w += (size_t)96 * 512 * 2;
  float* b1e = (float*)w; w += 2048;
  float* b2e = (float*)w; w += 512;
  size_t fixed = (size_t)(w - (char*)d_ws);

  const size_t satB = (size_t)96 * 17028 * 4;     // per-batch SAT bytes
  int nb = (ws_size >= fixed + 4 * satB + 4096) ? 4 : 1;

  float* SAT = (float*)w;

  if (nb == 4) {
    prepsat_kernel<<<992, 512, 0, stream>>>(W1, cb1, g1, be1, mu1, va1,
                                            W2, cb2, g2, be2, mu2, va2,
                                            x, V, b1e, W2e, b2e, SAT, 384);
    fused8_kernel<<<512, 512, 156672, stream>>>(SAT, V, b1e, W2e, b2e, out, 4, 0);
  } else {
    prepsat_kernel<<<608, 512, 0, stream>>>(W1, cb1, g1, be1, mu1, va1,
                                            W2, cb2, g2, be2, mu2, va2,
                                            x, V, b1e, W2e, b2e, SAT, 0);
    for (int b0 = 0; b0 < 4; ++b0) {
      satonly_kernel<<<96, 512, 0, stream>>>(x + (size_t)b0 * 96 * 16384, SAT);
      fused8_kernel<<<128, 512, 156672, stream>>>(SAT, V, b1e, W2e, b2e, out, 1, b0);
    }
  }
}